// Round 1
// baseline (491.986 us; speedup 1.0000x reference)
//
#include <hip/hip_runtime.h>

#define N_NODES 50000
#define N_PAD   50048   // 391*128, GEMM epilogue needs no row guards
#define N_EDGES 800000
#define N_GRAPHS 512
#define F_IN 256
#define F_H 128
#define F_CAT 256

// bucketed CSR build
#define BSHIFT 9
#define NB 98           // ceil(50000/512) buckets
#define CAP 10240       // edge capacity per bucket (mean 8163, 23 sigma slack)
#define EPB 3125        // edges per scatter block (256 blocks)

#define AGG_BLOCKS 2048 // persistent grid: exactly 8 blocks/CU on 256 CUs

typedef __attribute__((ext_vector_type(8))) short short8;
typedef __attribute__((ext_vector_type(4))) float f32x4;
typedef unsigned int uint;
typedef unsigned short ushort;

static __device__ __forceinline__ ushort f2bf(float f) {
    uint u = __float_as_uint(f);
    u += 0x7FFF + ((u >> 16) & 1);  // RNE
    return (ushort)(u >> 16);
}
static __device__ __forceinline__ float bflo(uint v) { return __uint_as_float(v << 16); }
static __device__ __forceinline__ float bfhi(uint v) { return __uint_as_float(v & 0xFFFF0000u); }
static __device__ __forceinline__ float bfu(ushort v) { return __uint_as_float((uint)v << 16); }

// async global->LDS, 16B per lane; lds base must be wave-uniform
#define GLL(g, l) __builtin_amdgcn_global_load_lds( \
    (const __attribute__((address_space(1))) unsigned int*)(g), \
    (__attribute__((address_space(3))) unsigned int*)(l), 16, 0, 0)

// ---------------------------------------------------------------------------
// S1: bucket-scatter edges. gcur is RELATIVE (zero-initialized by memset).
__global__ __launch_bounds__(256) void csr_scatter_kernel(
        const int* __restrict__ ei, int* __restrict__ gcur,
        uint* __restrict__ ebuf_td, uint* __restrict__ ebuf_bu) {
    __shared__ int lcnt[256];   // [dir*128 + bucket]
    __shared__ int lbase[256];
    int tid = threadIdx.x;
    lcnt[tid] = 0;
    __syncthreads();
    int e0 = blockIdx.x * EPB;
    for (int k = tid; k < EPB; k += 256) {
        int i = e0 + k;
        int s = ei[i], d = ei[N_EDGES + i];
        atomicAdd(&lcnt[d >> BSHIFT], 1);
        atomicAdd(&lcnt[128 + (s >> BSHIFT)], 1);
    }
    __syncthreads();
    if (tid < 2 * NB) {
        int dir = tid / NB, b = tid % NB;
        int c = lcnt[dir * 128 + b];
        lbase[dir * 128 + b] = c ? atomicAdd(&gcur[dir * NB + b], c) : 0;
    }
    __syncthreads();
    lcnt[tid] = 0;
    __syncthreads();
    for (int k = tid; k < EPB; k += 256) {
        int i = e0 + k;
        int s = ei[i], d = ei[N_EDGES + i];
        int bd = d >> BSHIFT, bs = s >> BSHIFT;
        int p = atomicAdd(&lcnt[bd], 1) + lbase[bd];
        ebuf_td[(size_t)bd * CAP + p] = (uint)s | ((uint)(d & 511) << 16);
        int q = atomicAdd(&lcnt[128 + bs], 1) + lbase[128 + bs];
        ebuf_bu[(size_t)bs * CAP + q] = (uint)d | ((uint)(s & 511) << 16);
    }
}

// ---------------------------------------------------------------------------
// S2: per-(bucket,dir) CSR build; also emits deg (u16) + dinv (free here,
// the node histogram already exists). Bucket-local scatter window.
__global__ __launch_bounds__(256) void csr_build_kernel(
        const uint* __restrict__ ebuf_td, const uint* __restrict__ ebuf_bu,
        const int* __restrict__ gcur,
        int* off_td, int* off_bu, ushort* deg_td, ushort* deg_bu,
        float* dinv_td, float* dinv_bu, ushort* csr_td, ushort* csr_bu) {
    int b = blockIdx.x, dir = blockIdx.y;
    const uint* ebuf = dir ? ebuf_bu : ebuf_td;
    int* off     = dir ? off_bu : off_td;
    ushort* deg  = dir ? deg_bu : deg_td;
    float* dinv  = dir ? dinv_bu : dinv_td;
    ushort* csr  = dir ? csr_bu : csr_td;
    __shared__ int cntL[512], offL[512], sm[256];
    int tid = threadIdx.x;
    cntL[tid] = 0; cntL[tid + 256] = 0;
    __syncthreads();
    int rbeg = b * CAP;
    int rend = rbeg + gcur[dir * NB + b];
    for (int k = rbeg + tid; k < rend; k += 256)
        atomicAdd(&cntL[ebuf[k] >> 16], 1);
    __syncthreads();
    int a0 = cntL[tid * 2], a1 = cntL[tid * 2 + 1];
    int ps = a0 + a1;
    sm[tid] = ps;
    __syncthreads();
    for (int o = 1; o < 256; o <<= 1) {
        int u = (tid >= o) ? sm[tid - o] : 0;
        __syncthreads();
        sm[tid] += u;
        __syncthreads();
    }
    int excl = sm[tid] - ps;
    offL[tid * 2] = excl;
    offL[tid * 2 + 1] = excl + a0;
    __syncthreads();
    int nbase = b << BSHIFT;
#pragma unroll
    for (int j = 0; j < 2; j++) {
        int nloc = tid + j * 256;
        int n = nbase + nloc;
        if (n < N_NODES) {
            off[n] = rbeg + offL[nloc];
            int c = cntL[nloc];
            deg[n] = (ushort)c;
            dinv[n] = rsqrtf((float)c + 1.0f);
        }
    }
    // pad rows (only needed once; bucket NB-1, dir both cover [50000, N_PAD))
    if (b == NB - 1) {
        int n = N_NODES + tid;
        if (n < N_PAD) dinv[n] = 1.0f;
    }
    cntL[tid] = offL[tid];
    cntL[tid + 256] = offL[tid + 256];
    __syncthreads();
    for (int k = rbeg + tid; k < rend; k += 256) {
        uint e = ebuf[k];
        int slot = atomicAdd(&cntL[e >> 16], 1);
        csr[rbeg + slot] = (ushort)(e & 0xFFFF);
    }
}

// ---------------------------------------------------------------------------
// Bt1[n][k]; Wt2[k][c] with c in concat([bu, td]) order.
__global__ void prep_w_kernel(const float* __restrict__ td_W1, const float* __restrict__ bu_W1,
                              const float* __restrict__ td_W2, const float* __restrict__ bu_W2,
                              ushort* __restrict__ Bt1, ushort* __restrict__ Wt2) {
    int n = blockIdx.x;   // 0..255
    int k = threadIdx.x;  // 0..255
    float w1 = (n < F_H) ? td_W1[(size_t)k * F_H + n] : bu_W1[(size_t)k * F_H + (n - F_H)];
    Bt1[(size_t)n * 256 + k] = f2bf(w1);
    if (k < 128) {
        float w2 = (n < F_H) ? bu_W2[(size_t)k * F_H + n]
                             : td_W2[(size_t)k * F_H + (n - F_H)];
        Wt2[(size_t)k * 256 + n] = f2bf(w2);
    }
}

// ---------------------------------------------------------------------------
// MFMA GEMM (layer 1): A = x f32 (in-register bf16 convert), B via GLL,
// C = linb bf16 row-scaled by branch dinv. 128x128 tile, BK=32, 4 waves.
__global__ __launch_bounds__(256) void gemm_mfma(
        const float* __restrict__ x, const ushort* __restrict__ Bt,
        ushort* __restrict__ C,
        const float* __restrict__ dinv_td, const float* __restrict__ dinv_bu) {
    __shared__ __align__(16) ushort As[128 * 32];
    __shared__ __align__(16) ushort Bs[128 * 32];
    int tid = threadIdx.x;
    int wave = tid >> 6, lane = tid & 63, quad = lane >> 4, l16 = lane & 15;
    size_t bm = (size_t)blockIdx.x * 128;
    size_t bn = (size_t)blockIdx.y * 128;
    const float* dsel = blockIdx.y ? dinv_bu : dinv_td;

    f32x4 acc[2][8];
    const f32x4 z4 = {0.f, 0.f, 0.f, 0.f};
#pragma unroll
    for (int i = 0; i < 2; i++)
#pragma unroll
        for (int j = 0; j < 8; j++) acc[i][j] = z4;

    // A staging (f32 -> bf16 in regs): thread covers rows ar+32j, kcols akq..+3
    int ar = tid >> 3;          // 0..31
    int akq = (tid & 7) * 4;    // 0..28
    // B staging via GLL: 512 x 16B chunks, 2 per thread
    int cb0 = wave * 64;
    int cb1 = 256 + wave * 64;
    int c0 = cb0 + lane, c1 = cb1 + lane;
    int r0 = c0 >> 2, s0 = (c0 & 3) * 8;
    int r1 = c1 >> 2, s1 = (c1 & 3) * 8;
    const ushort* b0p = Bt + (bn + r0) * 256 + s0;
    const ushort* b1p = Bt + (bn + r1) * 256 + s1;
    ushort* lB0 = Bs + cb0 * 8;
    ushort* lB1 = Bs + cb1 * 8;

    for (int kb = 0; kb < 8; kb++) {
        int k0 = kb * 32;
        float4 av[4];
#pragma unroll
        for (int j = 0; j < 4; j++) {
            size_t grow = bm + ar + j * 32;
            if (grow < N_NODES)
                av[j] = *(const float4*)(x + grow * F_IN + k0 + akq);
            else
                av[j] = make_float4(0.f, 0.f, 0.f, 0.f);
        }
        __syncthreads();  // previous iter's fragment reads done
        GLL(b0p + k0, lB0);
        GLL(b1p + k0, lB1);
#pragma unroll
        for (int j = 0; j < 4; j++) {
            ushort4 u;
            u.x = f2bf(av[j].x); u.y = f2bf(av[j].y);
            u.z = f2bf(av[j].z); u.w = f2bf(av[j].w);
            *(ushort4*)(As + (ar + j * 32) * 32 + akq) = u;
        }
        __syncthreads();  // drains vmcnt + lgkm, tiles ready
        short8 af0 = *(const short8*)(As + (wave * 32 + l16) * 32 + quad * 8);
        short8 af1 = *(const short8*)(As + (wave * 32 + 16 + l16) * 32 + quad * 8);
#pragma unroll
        for (int ct = 0; ct < 8; ct++) {
            short8 bfr = *(const short8*)(Bs + (ct * 16 + l16) * 32 + quad * 8);
            acc[0][ct] = __builtin_amdgcn_mfma_f32_16x16x32_bf16(af0, bfr, acc[0][ct], 0, 0, 0);
            acc[1][ct] = __builtin_amdgcn_mfma_f32_16x16x32_bf16(af1, bfr, acc[1][ct], 0, 0, 0);
        }
    }
#pragma unroll
    for (int rt = 0; rt < 2; rt++) {
#pragma unroll
        for (int r = 0; r < 4; r++) {
            size_t row = bm + wave * 32 + rt * 16 + quad * 4 + r;
            float dv = dsel[row];
#pragma unroll
            for (int ct = 0; ct < 8; ct++) {
                C[row * 256 + bn + ct * 16 + l16] = f2bf(acc[rt][ct][r] * dv);
            }
        }
    }
}

// ---------------------------------------------------------------------------
// Wave-gather v2: 16 lanes per edge row (uint4 = 8 bf16 cols per lane),
// 4 edge slots (q = lane>>4) concurrently; unroll-4 -> 16 edges in flight.
static __device__ __forceinline__ void acc8(float a[8], uint4 v) {
    a[0] += bflo(v.x); a[1] += bfhi(v.x);
    a[2] += bflo(v.y); a[3] += bfhi(v.y);
    a[4] += bflo(v.z); a[5] += bfhi(v.z);
    a[6] += bflo(v.w); a[7] += bfhi(v.w);
}

static __device__ __forceinline__ void gather_node4(
        const ushort* __restrict__ base, const ushort* __restrict__ csr,
        int kb, int ke, int q, float a[8]) {
    int k = kb;
    for (; k + 16 <= ke; k += 16) {
        int i0 = csr[k + q],      i1 = csr[k + 4 + q];
        int i2 = csr[k + 8 + q],  i3 = csr[k + 12 + q];
        uint4 v0 = *(const uint4*)(base + (size_t)i0 * F_CAT);
        uint4 v1 = *(const uint4*)(base + (size_t)i1 * F_CAT);
        uint4 v2 = *(const uint4*)(base + (size_t)i2 * F_CAT);
        uint4 v3 = *(const uint4*)(base + (size_t)i3 * F_CAT);
        acc8(a, v0); acc8(a, v1); acc8(a, v2); acc8(a, v3);
    }
    for (; k + 4 <= ke; k += 4) {
        uint4 v = *(const uint4*)(base + (size_t)csr[k + q] * F_CAT);
        acc8(a, v);
    }
    if (k + q < ke) {
        uint4 v = *(const uint4*)(base + (size_t)csr[k + q] * F_CAT);
        acc8(a, v);
    }
}

// ---------------------------------------------------------------------------
// Layer-1 aggregation, persistent-strided. Wave item = 2 nodes x 1 branch.
// h1s[n] = relu(dn*(self+neigh) + b1) * dn   (dinv pre-folded for layer 2)
__global__ __launch_bounds__(256, 8) void agg1_kernel(
        const ushort* __restrict__ linS, ushort* __restrict__ h1s,
        const ushort* __restrict__ csr_td, const int* __restrict__ off_td,
        const ushort* __restrict__ deg_td, const float* __restrict__ dinv_td,
        const ushort* __restrict__ csr_bu, const int* __restrict__ off_bu,
        const ushort* __restrict__ deg_bu, const float* __restrict__ dinv_bu,
        const float* __restrict__ b_td, const float* __restrict__ b_bu) {
    int lane = threadIdx.x & 63;
    int wid = blockIdx.x * 4 + (threadIdx.x >> 6);
    int br = wid & 1;           // branch fixed per wave
    int wq = wid >> 1;          // wave index within branch
    int nwq = gridDim.x * 2;    // waves per branch
    const ushort* csr = br ? csr_bu : csr_td;
    const int* off    = br ? off_bu : off_td;
    const ushort* deg = br ? deg_bu : deg_td;
    const float* dinv = br ? dinv_bu : dinv_td;
    const float* bias = br ? b_bu : b_td;
    int q = lane >> 4, c = lane & 15;
    int col = br * F_H + c * 8;
    const ushort* base = linS + col;
    float bs[8];
#pragma unroll
    for (int j = 0; j < 8; j++) bs[j] = bias[c * 8 + j];

    for (int t = wq; t < N_NODES / 2; t += nwq) {
        int n0 = t * 2;
#pragma unroll
        for (int j = 0; j < 2; j++) {
            int n = n0 + j;
            float a[8] = {0.f, 0.f, 0.f, 0.f, 0.f, 0.f, 0.f, 0.f};
            int kb = off[n];
            gather_node4(base, csr, kb, kb + deg[n], q, a);
#pragma unroll
            for (int u = 0; u < 8; u++) {
                a[u] += __shfl_xor(a[u], 16);
                a[u] += __shfl_xor(a[u], 32);
            }
            uint4 vs = *(const uint4*)(base + (size_t)n * F_CAT);  // self
            acc8(a, vs);
            float dn = dinv[n];
            if (q == 0) {
                float o[8];
#pragma unroll
                for (int u = 0; u < 8; u++) o[u] = fmaxf(a[u] * dn + bs[u], 0.f) * dn;
                uint4 pk;
                pk.x = (uint)f2bf(o[0]) | ((uint)f2bf(o[1]) << 16);
                pk.y = (uint)f2bf(o[2]) | ((uint)f2bf(o[3]) << 16);
                pk.z = (uint)f2bf(o[4]) | ((uint)f2bf(o[5]) << 16);
                pk.w = (uint)f2bf(o[6]) | ((uint)f2bf(o[7]) << 16);
                *(uint4*)(h1s + (size_t)n * F_CAT + col) = pk;
            }
        }
    }
}

// ---------------------------------------------------------------------------
// Layer-2 aggregation fused with pooling (pool-before-W2 algebra),
// persistent-strided. pooled_pre[g, col] += dn*(self + neigh).
__global__ __launch_bounds__(256, 8) void agg2_pool_kernel(
        const ushort* __restrict__ h1s, float* __restrict__ pooled_pre,
        const int* __restrict__ batch,
        const ushort* __restrict__ csr_td, const int* __restrict__ off_td,
        const ushort* __restrict__ deg_td, const float* __restrict__ dinv_td,
        const ushort* __restrict__ csr_bu, const int* __restrict__ off_bu,
        const ushort* __restrict__ deg_bu, const float* __restrict__ dinv_bu) {
    int lane = threadIdx.x & 63;
    int wid = blockIdx.x * 4 + (threadIdx.x >> 6);
    int br = wid & 1;
    int wq = wid >> 1;
    int nwq = gridDim.x * 2;
    const ushort* csr = br ? csr_bu : csr_td;
    const int* off    = br ? off_bu : off_td;
    const ushort* deg = br ? deg_bu : deg_td;
    const float* dinv = br ? dinv_bu : dinv_td;
    int q = lane >> 4, c = lane & 15;
    int col = br * F_H + c * 8;
    const ushort* base = h1s + col;

    for (int t = wq; t < N_NODES / 2; t += nwq) {
        int n0 = t * 2;
        float acc[8] = {0.f, 0.f, 0.f, 0.f, 0.f, 0.f, 0.f, 0.f};
        int gcur = batch[n0];
#pragma unroll
        for (int j = 0; j < 2; j++) {
            int n = n0 + j;
            int g = batch[n];
            if (g != gcur) {  // wave-uniform
                if (q == 0) {
                    float* pp = &pooled_pre[(size_t)gcur * F_CAT + col];
#pragma unroll
                    for (int u = 0; u < 8; u++) unsafeAtomicAdd(pp + u, acc[u]);
                }
#pragma unroll
                for (int u = 0; u < 8; u++) acc[u] = 0.f;
                gcur = g;
            }
            float a[8] = {0.f, 0.f, 0.f, 0.f, 0.f, 0.f, 0.f, 0.f};
            int kb = off[n];
            gather_node4(base, csr, kb, kb + deg[n], q, a);
#pragma unroll
            for (int u = 0; u < 8; u++) {
                a[u] += __shfl_xor(a[u], 16);
                a[u] += __shfl_xor(a[u], 32);
            }
            uint4 vs = *(const uint4*)(base + (size_t)n * F_CAT);  // self
            acc8(a, vs);
            float dn = dinv[n];
#pragma unroll
            for (int u = 0; u < 8; u++) acc[u] += a[u] * dn;
        }
        if (q == 0) {
            float* pp = &pooled_pre[(size_t)gcur * F_CAT + col];
#pragma unroll
            for (int u = 0; u < 8; u++) unsafeAtomicAdd(pp + u, acc[u]);
        }
    }
}

// ---------------------------------------------------------------------------
// Head: z = pooled_pre @ W2 (per branch) + cnt*b2 in concat([bu,td]) order,
// then MLP relu(z@pw1+pb1)@pw2+pb2. One block per graph.
__global__ __launch_bounds__(256) void head_kernel(
        const float* __restrict__ pooled_pre, const int* __restrict__ batch,
        const ushort* __restrict__ Wt2,
        const float* __restrict__ td_b2, const float* __restrict__ bu_b2,
        const float* __restrict__ pw1, const float* __restrict__ pb1,
        const float* __restrict__ pw2, const float* __restrict__ pb2,
        float* __restrict__ out) {
    int g = blockIdx.x;
    int tid = threadIdx.x;
    __shared__ float row[256], z[256], hid[256];
    row[tid] = pooled_pre[(size_t)g * 256 + tid];
    int lo = 0, hi = N_NODES;
    while (lo < hi) { int m = (lo + hi) >> 1; if (batch[m] < g) lo = m + 1; else hi = m; }
    int start = lo;
    lo = start; hi = N_NODES;
    while (lo < hi) { int m = (lo + hi) >> 1; if (batch[m] < g + 1) lo = m + 1; else hi = m; }
    float cnt = (float)(lo - start);
    __syncthreads();
    const float* rsel = (tid < 128) ? (row + F_H) : row;
    float b2 = (tid < 128) ? bu_b2[tid] : td_b2[tid - F_H];
    float acc = cnt * b2;
    for (int k = 0; k < F_H; k++) acc += rsel[k] * bfu(Wt2[(size_t)k * 256 + tid]);
    z[tid] = acc;
    __syncthreads();
    float h = pb1[tid];
    for (int k = 0; k < 256; k++) h += z[k] * pw1[(size_t)k * 256 + tid];
    hid[tid] = fmaxf(h, 0.f);
    __syncthreads();
    if (tid < 128) {
        float o = pb2[tid];
        for (int k = 0; k < 256; k++) o += hid[k] * pw2[(size_t)k * 128 + tid];
        out[(size_t)g * 128 + tid] = o;
    }
}

// ---------------------------------------------------------------------------
extern "C" void kernel_launch(void* const* d_in, const int* in_sizes, int n_in,
                              void* d_out, int out_size, void* d_ws, size_t ws_size,
                              hipStream_t stream) {
    const float* x     = (const float*)d_in[0];
    const int*   ei    = (const int*)d_in[1];
    const int*   batch = (const int*)d_in[2];
    const float* td_W1 = (const float*)d_in[4];
    const float* td_b1 = (const float*)d_in[5];
    const float* td_W2 = (const float*)d_in[6];
    const float* td_b2 = (const float*)d_in[7];
    const float* bu_W1 = (const float*)d_in[8];
    const float* bu_b1 = (const float*)d_in[9];
    const float* bu_W2 = (const float*)d_in[10];
    const float* bu_b2 = (const float*)d_in[11];
    const float* pw1   = (const float*)d_in[12];
    const float* pb1   = (const float*)d_in[13];
    const float* pw2   = (const float*)d_in[14];
    const float* pb2   = (const float*)d_in[15];
    float* out = (float*)d_out;

    // ---- workspace carve ----
    char* p = (char*)d_ws;
    auto alloc = [&](size_t bytes) { void* r = (void*)p; p += (bytes + 255) & ~(size_t)255; return r; };
    // single memset region: gcur (1 KB) + pooled_pre (512 KB)
    char* zreg = (char*)alloc(1024 + (size_t)N_GRAPHS * F_CAT * sizeof(float));
    int* gcur = (int*)zreg;
    float* pooled_pre = (float*)(zreg + 1024);
    uint* ebuf_td = (uint*)alloc((size_t)NB * CAP * sizeof(uint));
    uint* ebuf_bu = (uint*)alloc((size_t)NB * CAP * sizeof(uint));
    ushort* csr_td = (ushort*)alloc((size_t)NB * CAP * sizeof(ushort));
    ushort* csr_bu = (ushort*)alloc((size_t)NB * CAP * sizeof(ushort));
    int* off_td = (int*)alloc((size_t)N_NODES * sizeof(int));
    int* off_bu = (int*)alloc((size_t)N_NODES * sizeof(int));
    ushort* deg_td = (ushort*)alloc((size_t)N_NODES * sizeof(ushort));
    ushort* deg_bu = (ushort*)alloc((size_t)N_NODES * sizeof(ushort));
    float* dinv_td = (float*)alloc((size_t)N_PAD * sizeof(float));
    float* dinv_bu = (float*)alloc((size_t)N_PAD * sizeof(float));
    ushort* Bt1 = (ushort*)alloc((size_t)256 * 256 * sizeof(ushort));
    ushort* Wt2 = (ushort*)alloc((size_t)128 * 256 * sizeof(ushort));
    ushort* linb = (ushort*)alloc((size_t)N_PAD * F_CAT * sizeof(ushort));
    ushort* h1s  = (ushort*)alloc((size_t)N_PAD * F_CAT * sizeof(ushort));

    hipMemsetAsync(zreg, 0, 1024 + (size_t)N_GRAPHS * F_CAT * sizeof(float), stream);

    // ---- weights prep ----
    prep_w_kernel<<<256, 256, 0, stream>>>(td_W1, bu_W1, td_W2, bu_W2, Bt1, Wt2);

    // ---- graph structure (bucketed counting sort; csr_build emits dinv) ----
    csr_scatter_kernel<<<N_EDGES / EPB, 256, 0, stream>>>(ei, gcur, ebuf_td, ebuf_bu);
    csr_build_kernel<<<dim3(NB, 2), 256, 0, stream>>>(ebuf_td, ebuf_bu, gcur,
        off_td, off_bu, deg_td, deg_bu, dinv_td, dinv_bu, csr_td, csr_bu);

    // ---- layer 1: GEMM (f32 A, in-register cvt; dinv ready) ----
    dim3 gg(N_PAD / 128, 2);
    gemm_mfma<<<gg, 256, 0, stream>>>(x, Bt1, linb, dinv_td, dinv_bu);
    agg1_kernel<<<AGG_BLOCKS, 256, 0, stream>>>(linb, h1s,
        csr_td, off_td, deg_td, dinv_td, csr_bu, off_bu, deg_bu, dinv_bu, td_b1, bu_b1);

    // ---- layer 2: aggregation + pool (W2 deferred to head) ----
    agg2_pool_kernel<<<AGG_BLOCKS, 256, 0, stream>>>(h1s, pooled_pre, batch,
        csr_td, off_td, deg_td, dinv_td, csr_bu, off_bu, deg_bu, dinv_bu);

    // ---- head: W2 matvec + cnt*b2 + MLP ----
    head_kernel<<<N_GRAPHS, 256, 0, stream>>>(pooled_pre, batch, Wt2,
        td_b2, bu_b2, pw1, pb1, pw2, pb2, out);
}